// Round 7
// baseline (232.560 us; speedup 1.0000x reference)
//
#include <hip/hip_runtime.h>
#include <math.h>

#define NNODES 50000
#define NEDGE  800000
#define NG     3
#define GE     (NG*NEDGE)            // 2,400,000 combined edges
#define NBUK   2048                  // row buckets: bucket(r) = r*128/3125 -> 24/25 rows each
#define OS     (NBUK + 1)            // 2049, off1 row stride
#define CH     6000                  // edges per bin block; 400*6000 == GE exactly
#define NBLK   400                   // bin blocks (< 512: one segment per k_agg thread)
#define GBLK   391                   // gemm blocks of 128 rows (391*128 = 50048)
#define STGCAP 1536                  // raw record cap per bucket (mean 1172, +10.7 sigma)
#define NPH    7                     // col phases: col>>13 -> 8192-col windows (2MB of hbits)
#define MAXG   175                   // max groups = NPH * 25
#define SCAP   2112                  // sorted cap: STGCAP + MAXG*3 = 2061 -> never overflows

typedef __attribute__((ext_vector_type(8))) short bf16x8;
typedef __attribute__((ext_vector_type(4))) float f32x4;

// fp32 -> bf16 round-to-nearest-even (no NaN inputs here)
__device__ __forceinline__ unsigned short f2bf(float f) {
    unsigned u = __float_as_uint(f);
    return (unsigned short)((u + 0x7fffu + ((u >> 16) & 1u)) >> 16);
}

// bucket of row r: floor(r*2048/50000) = floor(r*128/3125); exact for r < 50000
__device__ __forceinline__ int bucket_of(unsigned r) {
    return (int)((r * 128u) / 3125u);
}

// ---------------------------------------------------------------------------
// K0: swizzle W (fp32 [128][128], row=out) into bf16 MFMA B-fragment order,
// ONCE (r0-proven). r2-r5 fused this into every gemm block = 391x the VALU.
// ---------------------------------------------------------------------------
__global__ void k_wprep(const float* __restrict__ W, uint4* __restrict__ Wf) {
    const int t = threadIdx.x;   // 256 threads, 1 block
    for (int i = t; i < 2048; i += 256) {
        const int nt   = i >> 8;         // 0..7
        const int kc   = (i >> 6) & 3;   // 0..3
        const int lane = i & 63;
        const int n  = nt * 16 + (lane & 15);
        const int k0 = kc * 32 + (lane >> 4) * 8;
        const float* src = W + (size_t)n * 128 + k0;
        unsigned u0 = (unsigned)f2bf(src[0]) | ((unsigned)f2bf(src[1]) << 16);
        unsigned u1 = (unsigned)f2bf(src[2]) | ((unsigned)f2bf(src[3]) << 16);
        unsigned u2 = (unsigned)f2bf(src[4]) | ((unsigned)f2bf(src[5]) << 16);
        unsigned u3 = (unsigned)f2bf(src[6]) | ((unsigned)f2bf(src[7]) << 16);
        Wf[i] = make_uint4(u0, u1, u2, u3);
    }
}

// ---------------------------------------------------------------------------
// K1: h = X @ W^T, bf16 MFMA, 128 rows/block (r3-r5 proven body). Standalone:
// own VGPR budget; grid 391 <= 512 slots even at 2 blocks/CU -> single pass
// (the fused front forced gemm's ~100 VGPR on 791 blocks = 1.55 passes).
// ---------------------------------------------------------------------------
__global__ __launch_bounds__(512) void k_gemm(const float* __restrict__ X,
                                              const uint4* __restrict__ Wf,
                                              unsigned short* __restrict__ hb16) {
    __shared__ __align__(16) char smem[34816];
    const int t = threadIdx.x;
    uint4* Wl = (uint4*)smem;   // 2048 records = 32KB, pre-swizzled
#pragma unroll
    for (int j = 0; j < 4; ++j) Wl[t + j * 512] = Wf[t + j * 512];
    __syncthreads();

    const int w    = t >> 6;
    const int lane = t & 63;
    const int q    = lane >> 4;
    const int ml   = lane & 15;
    const int m0   = blockIdx.x * 128 + w * 16;

    int xr = m0 + ml; if (xr >= NNODES) xr = NNODES - 1;   // clamp (stores guarded)
    const float* xrow = X + (size_t)xr * 128;

    bf16x8 xf[4];
#pragma unroll
    for (int kc = 0; kc < 4; ++kc) {
        const int k0 = kc * 32 + q * 8;
        float4 a = *(const float4*)(xrow + k0);
        float4 b = *(const float4*)(xrow + k0 + 4);
        bf16x8 v;
        v[0] = (short)f2bf(a.x); v[1] = (short)f2bf(a.y);
        v[2] = (short)f2bf(a.z); v[3] = (short)f2bf(a.w);
        v[4] = (short)f2bf(b.x); v[5] = (short)f2bf(b.y);
        v[6] = (short)f2bf(b.z); v[7] = (short)f2bf(b.w);
        xf[kc] = v;
    }

    f32x4 acc[8];
#pragma unroll
    for (int nt = 0; nt < 8; ++nt) acc[nt] = (f32x4){0.f, 0.f, 0.f, 0.f};
#pragma unroll
    for (int nt = 0; nt < 8; ++nt)
#pragma unroll
        for (int kc = 0; kc < 4; ++kc) {
            const bf16x8 wf = *(const bf16x8*)&Wl[(nt * 4 + kc) * 64 + lane];
            acc[nt] = __builtin_amdgcn_mfma_f32_16x16x32_bf16(xf[kc], wf, acc[nt], 0, 0, 0);
        }
    __syncthreads();   // done reading Wl; reuse region for transpose

    // per-wave 16x128 u16 tile, row stride 136 u16 (16B-aligned, banks spread)
    unsigned short* hst = (unsigned short*)smem + w * 2176;
#pragma unroll
    for (int nt = 0; nt < 8; ++nt)
#pragma unroll
        for (int r = 0; r < 4; ++r)
            hst[(q * 4 + r) * 136 + nt * 16 + ml] = f2bf(acc[nt][r]);
    __syncthreads();

    // coalesced store: 16-lane groups write full 256B rows
#pragma unroll
    for (int i = 0; i < 4; ++i) {
        const int chunk = i * 64 + lane;
        const int lr    = chunk >> 4;
        const int cc    = chunk & 15;
        const int row   = m0 + lr;
        const uint4 v = *(const uint4*)(hst + lr * 136 + cc * 8);
        if (row < NNODES)
            ((uint4*)(hb16 + (size_t)row * 128))[cc] = v;
    }
}

// ---------------------------------------------------------------------------
// K2: bin CH=6000 edges into 2048 row-buckets (r5-proven body, standalone:
// 20.2KB LDS, low VGPR -> 4+ blocks/CU, 400 blocks = single pass).
// ---------------------------------------------------------------------------
__global__ __launch_bounds__(512) void k_bin(const int* __restrict__ rows,
                                             const int* __restrict__ cols,
                                             const float* __restrict__ vals,
                                             const float* __restrict__ alpha,
                                             uint2* __restrict__ out1,
                                             unsigned short* __restrict__ off1) {
    __shared__ unsigned short rnk[CH];     // 12,000 B
    __shared__ int sA[NBUK];               //  8,192 B
    const int t     = threadIdx.x;
    const int bb    = blockIdx.x;
    const int start = bb * CH;                           // end = start+CH (exact fit)

    const float g0 = 1.0f / (1.0f + __expf(-alpha[0]));
    const float g1 = 1.0f / (1.0f + __expf(-alpha[1]));
    const float g2 = 1.0f / (1.0f + __expf(-alpha[2]));

#pragma unroll
    for (int j = 0; j < 4; ++j) sA[t + j * 512] = 0;
    __syncthreads();

    // pass 1: histogram + rank (rows stream only)
    for (int k = t; k < CH; k += 512) {
        const int r = rows[start + k];
        rnk[k] = (unsigned short)atomicAdd(&sA[bucket_of((unsigned)r)], 1);
    }
    __syncthreads();

    // in-place inclusive scan over 2048 (11 steps)
    for (int off = 1; off < 2048; off <<= 1) {
        int v[4];
#pragma unroll
        for (int j = 0; j < 4; ++j) {
            const int i = t + j * 512;
            v[j] = sA[i] + ((i >= off) ? sA[i - off] : 0);
        }
        __syncthreads();
#pragma unroll
        for (int j = 0; j < 4; ++j) sA[t + j * 512] = v[j];
        __syncthreads();
    }

    // off1 = exclusive offsets (values <= 6000 -> u16)
    for (int b = t; b < NBUK; b += 512)
        off1[(size_t)bb * OS + b] = (unsigned short)(b ? sA[b - 1] : 0);
    if (t == 0) off1[(size_t)bb * OS + NBUK] = (unsigned short)sA[NBUK - 1];

    // pass 2: re-read edge streams (contiguous, L2-hot), scatter to out1
    for (int k = t; k < CH; k += 512) {
        const int idx = start + k;
        const int r = rows[idx];
        const int c = cols[idx];
        const float v = vals[idx];
        const float gv = v * (idx < NEDGE ? g0 : (idx < 2 * NEDGE ? g1 : g2));
        const int b = bucket_of((unsigned)r);
        const int pos = (b ? sA[b - 1] : 0) + (int)rnk[k];
        uint2 rec;
        rec.x = ((unsigned)r << 16) | (unsigned)c;
        rec.y = __float_as_uint(gv);
        out1[(size_t)bb * CH + pos] = rec;
    }
}

// ---------------------------------------------------------------------------
// K3: one block (512 thr = 8 waves) per 24/25-row bucket, phase-sorted gather
// (r5-proven verbatim: 93us, FETCH 243MB, Occ 68%). 2048 blocks at 4/CU =
// exactly 2 passes.
// ---------------------------------------------------------------------------
__global__ __launch_bounds__(512, 8) void k_agg(const unsigned* __restrict__ hbits,
                                                const uint2* __restrict__ out1,
                                                const unsigned short* __restrict__ off1,
                                                float* __restrict__ out) {
    __shared__ __align__(16) uint2          stg[STGCAP];   // 12,288 B
    __shared__ __align__(16) unsigned short colS[SCAP];    //  4,224 B
    __shared__ __align__(16) float          valS[SCAP];    //  8,448 B
    __shared__ int rh[MAXG], grpBase[MAXG + 1], gcur[MAXG];
    __shared__ int sA[512];
    const int t = threadIdx.x;
    const int b = blockIdx.x;

    // bucket row range: [ceil(b*3125/128), ceil((b+1)*3125/128))
    const int sstart = (b * 3125 + 127) >> 7;
    const int send   = ((b + 1) * 3125 + 127) >> 7;
    const int width  = send - sstart;                      // 24 or 25
    const int ngrp   = NPH * width;                        // 168 or 175

    if (t < MAXG) rh[t] = 0;

    // one segment per thread (threads >= NBLK idle here)
    int s0 = 0, e0 = 0;
    if (t < NBLK) {
        s0 = off1[(size_t)t * OS + b];
        e0 = off1[(size_t)t * OS + b + 1];
    }
    const int len = e0 - s0;
    sA[t] = len;
    __syncthreads();

    // 512-wide inclusive scan -> per-thread staging base
    for (int off = 1; off < 512; off <<= 1) {
        const int v = sA[t] + ((t >= off) ? sA[t - off] : 0);
        __syncthreads();
        sA[t] = v;
        __syncthreads();
    }
    const int base = sA[t] - len;
    __syncthreads();   // sA reused below

    // P1: single global read; stage + per-(phase,row) histogram
    {
        const uint2* seg = out1 + (size_t)t * CH;
        int p = base;
        for (int i = s0; i < e0; ++i, ++p) {
            const uint2 rec = seg[i];
            if (p < STGCAP) {
                stg[p] = rec;
                const int lr = (int)(rec.x >> 16) - sstart;
                const int ph = (int)((rec.x & 0xffffu) >> 13);
                atomicAdd(&rh[ph * width + lr], 1);
            }
        }
    }
    __syncthreads();

    // P2: scan of 4-padded group counts -> 4-aligned group bases + pad fill
    if (t < 256) sA[t] = (t < ngrp) ? ((rh[t] + 3) & ~3) : 0;
    __syncthreads();
    for (int off = 1; off < 256; off <<= 1) {
        int v = 0;
        if (t < 256) v = sA[t] + ((t >= off) ? sA[t - off] : 0);
        __syncthreads();
        if (t < 256) sA[t] = v;
        __syncthreads();
    }
    if (t < ngrp) {
        const int pc = (rh[t] + 3) & ~3;
        const int gb = sA[t] - pc;
        grpBase[t] = gb;
        gcur[t]    = gb;
        for (int k = gb + rh[t]; k < gb + pc; ++k) { colS[k] = 0; valS[k] = 0.f; }
    }
    __syncthreads();
    if (t == 0) grpBase[ngrp] = sA[ngrp - 1];
    __syncthreads();

    // P3: LDS->LDS scatter straight into (phase,row)-sorted position
    {
        const int lim = (base + len < STGCAP) ? (base + len) : STGCAP;
        for (int k = base; k < lim; ++k) {
            const uint2 rec = stg[k];
            const int lr = (int)(rec.x >> 16) - sstart;
            const int ph = (int)((rec.x & 0xffffu) >> 13);
            const int pos = atomicAdd(&gcur[ph * width + lr], 1);
            colS[pos] = (unsigned short)(rec.x & 0xffffu);
            valS[pos] = __uint_as_float(rec.y);
        }
    }
    __syncthreads();

    // P4: phase-major gather. Wave w owns rows lr = w+8*ri (ri<4), acc in regs.
    const int w    = t >> 6;
    const int lane = t & 63;
    float2 acc[4];
#pragma unroll
    for (int ri = 0; ri < 4; ++ri) acc[ri] = make_float2(0.f, 0.f);

    for (int ph = 0; ph < NPH; ++ph) {
#pragma unroll
        for (int ri = 0; ri < 4; ++ri) {
            const int lr = w + ri * 8;
            if (lr < width) {
                const int g = ph * width + lr;
                const int s = grpBase[g];
                const int e = grpBase[g + 1];
                int i = s;
                for (; i + 8 <= e; i += 8) {
                    const uint2  ca = *(const uint2*)&colS[i];
                    const uint2  cb = *(const uint2*)&colS[i + 4];
                    const float4 v0 = *(const float4*)&valS[i];
                    const float4 v1 = *(const float4*)&valS[i + 4];
                    unsigned hb[8];
                    hb[0] = hbits[(size_t)(ca.x & 0xffffu) * 64 + lane];
                    hb[1] = hbits[(size_t)(ca.x >> 16)     * 64 + lane];
                    hb[2] = hbits[(size_t)(ca.y & 0xffffu) * 64 + lane];
                    hb[3] = hbits[(size_t)(ca.y >> 16)     * 64 + lane];
                    hb[4] = hbits[(size_t)(cb.x & 0xffffu) * 64 + lane];
                    hb[5] = hbits[(size_t)(cb.x >> 16)     * 64 + lane];
                    hb[6] = hbits[(size_t)(cb.y & 0xffffu) * 64 + lane];
                    hb[7] = hbits[(size_t)(cb.y >> 16)     * 64 + lane];
                    const float vv[8] = {v0.x, v0.y, v0.z, v0.w, v1.x, v1.y, v1.z, v1.w};
#pragma unroll
                    for (int j = 0; j < 8; ++j) {
                        acc[ri].x += vv[j] * __uint_as_float(hb[j] << 16);
                        acc[ri].y += vv[j] * __uint_as_float(hb[j] & 0xffff0000u);
                    }
                }
                if (i < e) {   // exactly one 4-wide remainder (padded to 4)
                    const uint2  ca = *(const uint2*)&colS[i];
                    const float4 v0 = *(const float4*)&valS[i];
                    unsigned hb[4];
                    hb[0] = hbits[(size_t)(ca.x & 0xffffu) * 64 + lane];
                    hb[1] = hbits[(size_t)(ca.x >> 16)     * 64 + lane];
                    hb[2] = hbits[(size_t)(ca.y & 0xffffu) * 64 + lane];
                    hb[3] = hbits[(size_t)(ca.y >> 16)     * 64 + lane];
                    const float vv[4] = {v0.x, v0.y, v0.z, v0.w};
#pragma unroll
                    for (int j = 0; j < 4; ++j) {
                        acc[ri].x += vv[j] * __uint_as_float(hb[j] << 16);
                        acc[ri].y += vv[j] * __uint_as_float(hb[j] & 0xffff0000u);
                    }
                }
            }
        }
    }

#pragma unroll
    for (int ri = 0; ri < 4; ++ri) {
        const int lr = w + ri * 8;
        if (lr < width) {
            const int row = sstart + lr;
            ((float2*)out)[(size_t)row * 64 + lane] = acc[ri];
        }
    }
}

extern "C" void kernel_launch(void* const* d_in, const int* in_sizes, int n_in,
                              void* d_out, int out_size, void* d_ws, size_t ws_size,
                              hipStream_t stream) {
    const float* X     = (const float*)d_in[0];
    const float* W     = (const float*)d_in[1];
    const float* alpha = (const float*)d_in[2];
    const int*   rows  = (const int*)d_in[3];
    const int*   cols  = (const int*)d_in[4];
    const float* vals  = (const float*)d_in[5];
    float* out = (float*)d_out;

    // workspace layout (33,671,968 B <= proven 33,870,176 footprint)
    char* ws = (char*)d_ws;
    unsigned*       hbits = (unsigned*)(ws + 0);              // 12,800,000 B
    unsigned short* hb16  = (unsigned short*)(ws + 0);        // same bytes, u16 view
    uint2*          out1  = (uint2*)(ws + 12800000);          // 400*6000*8 = 19,200,000 B
    unsigned short* off1  = (unsigned short*)(ws + 32000000); // 400*2049*2 =  1,639,200 B
    uint4*          Wf    = (uint4*)(ws + 33639200);          //     32,768 B

    hipLaunchKernelGGL(k_wprep, dim3(1), dim3(256), 0, stream, W, Wf);
    hipLaunchKernelGGL(k_bin, dim3(NBLK), dim3(512), 0, stream,
                       rows, cols, vals, alpha, out1, off1);
    hipLaunchKernelGGL(k_gemm, dim3(GBLK), dim3(512), 0, stream, X, Wf, hb16);
    hipLaunchKernelGGL(k_agg, dim3(NBUK), dim3(512), 0, stream,
                       hbits, out1, off1, out);
}

// Round 8
// 217.143 us; speedup vs baseline: 1.0710x; 1.0710x over previous
//
#include <hip/hip_runtime.h>
#include <math.h>

#define NNODES 50000
#define NEDGE  800000
#define NG     3
#define GE     (NG*NEDGE)            // 2,400,000 combined edges
#define NBUK   2048                  // row buckets: bucket(r) = r*128/3125 -> 24/25 rows each
#define OS     (NBUK + 1)            // 2049, off1 row stride
#define CH     9375                  // edges per bin block; 256*9375 == GE exactly
#define NBLK   256                   // bin blocks; each k_agg segment walked by TWO threads
#define GBLK   391                   // gemm jobs of 128 rows (391*128 = 50048)
#define FGRID  (GBLK + NBLK)         // 647 fused front blocks (single pass at 4/CU)
#define STGCAP 1536                  // raw record cap per bucket (mean 1172, +10.7 sigma)
#define NPH    7                     // col phases: col>>13 -> 8192-col windows (2MB of hbits)
#define MAXG   175                   // max groups = NPH * 25
#define SCAP   2112                  // sorted cap: STGCAP + MAXG*3 = 2061 -> never overflows

typedef __attribute__((ext_vector_type(8))) short bf16x8;
typedef __attribute__((ext_vector_type(4))) float f32x4;

// fp32 -> bf16 round-to-nearest-even (no NaN inputs here)
__device__ __forceinline__ unsigned short f2bf(float f) {
    unsigned u = __float_as_uint(f);
    return (unsigned short)((u + 0x7fffu + ((u >> 16) & 1u)) >> 16);
}

// bucket of row r: floor(r*2048/50000) = floor(r*128/3125); exact for r < 50000
__device__ __forceinline__ int bucket_of(unsigned r) {
    return (int)((r * 128u) / 3125u);
}

// ---------------------------------------------------------------------------
// K_FRONT: fused {W-swizzle + GEMM} | {edge binning}  (r5-proven shape; r7
// proved splitting costs ~10us/dispatch). Bin path: 256 blocks of CH=9375
// edges -> bigger per-bucket segments (4.6 rec) to cut k_agg's out1 read
// amplification (~63MB -> ~34MB of 64B lines).
// ---------------------------------------------------------------------------
__global__ __launch_bounds__(512) void k_front(const float* __restrict__ X,
                                               const float* __restrict__ W,
                                               const int* __restrict__ rows,
                                               const int* __restrict__ cols,
                                               const float* __restrict__ vals,
                                               const float* __restrict__ alpha,
                                               unsigned short* __restrict__ hb16,
                                               uint2* __restrict__ out1,
                                               unsigned short* __restrict__ off1) {
    __shared__ __align__(16) char smem[34816];
    const int t = threadIdx.x;

    if (blockIdx.x < GBLK) {
        // ---------------- GEMM path (r5-proven verbatim) ----------------
        uint4* Wl = (uint4*)smem;   // 2048 records = 32KB, MFMA B-fragment order
        for (int i = t; i < 2048; i += 512) {
            const int nt   = i >> 8;
            const int kc   = (i >> 6) & 3;
            const int lane = i & 63;
            const int n  = nt * 16 + (lane & 15);
            const int k0 = kc * 32 + (lane >> 4) * 8;
            const float* src = W + (size_t)n * 128 + k0;
            float4 a = *(const float4*)(src);
            float4 b = *(const float4*)(src + 4);
            unsigned u0 = (unsigned)f2bf(a.x) | ((unsigned)f2bf(a.y) << 16);
            unsigned u1 = (unsigned)f2bf(a.z) | ((unsigned)f2bf(a.w) << 16);
            unsigned u2 = (unsigned)f2bf(b.x) | ((unsigned)f2bf(b.y) << 16);
            unsigned u3 = (unsigned)f2bf(b.z) | ((unsigned)f2bf(b.w) << 16);
            Wl[i] = make_uint4(u0, u1, u2, u3);
        }
        __syncthreads();

        const int w    = t >> 6;
        const int lane = t & 63;
        const int q    = lane >> 4;
        const int ml   = lane & 15;
        const int m0   = blockIdx.x * 128 + w * 16;

        int xr = m0 + ml; if (xr >= NNODES) xr = NNODES - 1;   // clamp (stores guarded)
        const float* xrow = X + (size_t)xr * 128;

        bf16x8 xf[4];
#pragma unroll
        for (int kc = 0; kc < 4; ++kc) {
            const int k0 = kc * 32 + q * 8;
            float4 a = *(const float4*)(xrow + k0);
            float4 b = *(const float4*)(xrow + k0 + 4);
            bf16x8 v;
            v[0] = (short)f2bf(a.x); v[1] = (short)f2bf(a.y);
            v[2] = (short)f2bf(a.z); v[3] = (short)f2bf(a.w);
            v[4] = (short)f2bf(b.x); v[5] = (short)f2bf(b.y);
            v[6] = (short)f2bf(b.z); v[7] = (short)f2bf(b.w);
            xf[kc] = v;
        }

        f32x4 acc[8];
#pragma unroll
        for (int nt = 0; nt < 8; ++nt) acc[nt] = (f32x4){0.f, 0.f, 0.f, 0.f};
#pragma unroll
        for (int nt = 0; nt < 8; ++nt)
#pragma unroll
            for (int kc = 0; kc < 4; ++kc) {
                const bf16x8 wf = *(const bf16x8*)&Wl[(nt * 4 + kc) * 64 + lane];
                acc[nt] = __builtin_amdgcn_mfma_f32_16x16x32_bf16(xf[kc], wf, acc[nt], 0, 0, 0);
            }
        __syncthreads();   // done reading Wl; reuse region for transpose

        // per-wave 16x128 u16 tile, row stride 136 u16 (16B-aligned, banks spread)
        unsigned short* hst = (unsigned short*)smem + w * 2176;
#pragma unroll
        for (int nt = 0; nt < 8; ++nt)
#pragma unroll
            for (int r = 0; r < 4; ++r)
                hst[(q * 4 + r) * 136 + nt * 16 + ml] = f2bf(acc[nt][r]);
        __syncthreads();

        // coalesced store: 16-lane groups write full 256B rows
#pragma unroll
        for (int i = 0; i < 4; ++i) {
            const int chunk = i * 64 + lane;
            const int lr    = chunk >> 4;
            const int cc    = chunk & 15;
            const int row   = m0 + lr;
            const uint4 v = *(const uint4*)(hst + lr * 136 + cc * 8);
            if (row < NNODES)
                ((uint4*)(hb16 + (size_t)row * 128))[cc] = v;
        }
    } else {
        // ---------------- BIN path (CH=9375, 26.9KB LDS) ----------------
        unsigned short* rnk = (unsigned short*)smem;         // 18,750 B
        int*            sA  = (int*)(smem + 18752);          //  8,192 B
        const int bb    = blockIdx.x - GBLK;
        const int start = bb * CH;                           // end = start+CH (exact fit)

        const float g0 = 1.0f / (1.0f + __expf(-alpha[0]));
        const float g1 = 1.0f / (1.0f + __expf(-alpha[1]));
        const float g2 = 1.0f / (1.0f + __expf(-alpha[2]));

#pragma unroll
        for (int j = 0; j < 4; ++j) sA[t + j * 512] = 0;
        __syncthreads();

        // pass 1: histogram + rank (rows stream only)
        for (int k = t; k < CH; k += 512) {
            const int r = rows[start + k];
            rnk[k] = (unsigned short)atomicAdd(&sA[bucket_of((unsigned)r)], 1);
        }
        __syncthreads();

        // in-place inclusive scan over 2048 (11 steps)
        for (int off = 1; off < 2048; off <<= 1) {
            int v[4];
#pragma unroll
            for (int j = 0; j < 4; ++j) {
                const int i = t + j * 512;
                v[j] = sA[i] + ((i >= off) ? sA[i - off] : 0);
            }
            __syncthreads();
#pragma unroll
            for (int j = 0; j < 4; ++j) sA[t + j * 512] = v[j];
            __syncthreads();
        }

        // off1 = exclusive offsets (values <= 9375 -> u16)
        for (int b = t; b < NBUK; b += 512)
            off1[(size_t)bb * OS + b] = (unsigned short)(b ? sA[b - 1] : 0);
        if (t == 0) off1[(size_t)bb * OS + NBUK] = (unsigned short)sA[NBUK - 1];

        // pass 2: re-read edge streams (contiguous, L2-hot), scatter to out1
        for (int k = t; k < CH; k += 512) {
            const int idx = start + k;
            const int r = rows[idx];
            const int c = cols[idx];
            const float v = vals[idx];
            const float gv = v * (idx < NEDGE ? g0 : (idx < 2 * NEDGE ? g1 : g2));
            const int b = bucket_of((unsigned)r);
            const int pos = (b ? sA[b - 1] : 0) + (int)rnk[k];
            uint2 rec;
            rec.x = ((unsigned)r << 16) | (unsigned)c;
            rec.y = __float_as_uint(gv);
            out1[(size_t)bb * CH + pos] = rec;
        }
    }
}

// ---------------------------------------------------------------------------
// K_AGG: one block (512 thr = 8 waves) per 24/25-row bucket, phase-sorted
// gather (r5-proven 93us core). r8 changes:
//  - 256 source segments, each walked by TWO threads (halves) -> all 512
//    threads active in P1, out1 line fetches ~34MB (was ~63MB @ 400 srcs).
//  - P4 gather via 32-bit saddr form: hbits[(col<<6)|lane].
// ---------------------------------------------------------------------------
__global__ __launch_bounds__(512, 8) void k_agg(const unsigned* __restrict__ hbits,
                                                const uint2* __restrict__ out1,
                                                const unsigned short* __restrict__ off1,
                                                float* __restrict__ out) {
    __shared__ __align__(16) uint2          stg[STGCAP];   // 12,288 B
    __shared__ __align__(16) unsigned short colS[SCAP];    //  4,224 B
    __shared__ __align__(16) float          valS[SCAP];    //  8,448 B
    __shared__ int rh[MAXG], grpBase[MAXG + 1], gcur[MAXG];
    __shared__ int sA[512];
    const int t = threadIdx.x;
    const int b = blockIdx.x;

    // bucket row range: [ceil(b*3125/128), ceil((b+1)*3125/128))
    const int sstart = (b * 3125 + 127) >> 7;
    const int send   = ((b + 1) * 3125 + 127) >> 7;
    const int width  = send - sstart;                      // 24 or 25
    const int ngrp   = NPH * width;                        // 168 or 175

    if (t < MAXG) rh[t] = 0;

    // two threads per segment: t&255 = segment, t>>8 = half
    const int seg  = t & 255;
    const int s0f  = off1[(size_t)seg * OS + b];
    const int e0f  = off1[(size_t)seg * OS + b + 1];
    const int lenf = e0f - s0f;
    const int mid  = s0f + ((lenf + 1) >> 1);
    const int half = t >> 8;                               // 0 or 1
    const int s0   = half ? mid : s0f;
    const int e0   = half ? e0f : mid;
    const int len  = e0 - s0;
    sA[t] = len;
    __syncthreads();

    // 512-wide inclusive scan -> per-thread staging base
    for (int off = 1; off < 512; off <<= 1) {
        const int v = sA[t] + ((t >= off) ? sA[t - off] : 0);
        __syncthreads();
        sA[t] = v;
        __syncthreads();
    }
    const int base = sA[t] - len;
    __syncthreads();   // sA reused below

    // P1: single global read; stage + per-(phase,row) histogram
    {
        const uint2* segp = out1 + (size_t)seg * CH;
        int p = base;
        for (int i = s0; i < e0; ++i, ++p) {
            const uint2 rec = segp[i];
            if (p < STGCAP) {
                stg[p] = rec;
                const int lr = (int)(rec.x >> 16) - sstart;
                const int ph = (int)((rec.x & 0xffffu) >> 13);
                atomicAdd(&rh[ph * width + lr], 1);
            }
        }
    }
    __syncthreads();

    // P2: scan of 4-padded group counts -> 4-aligned group bases + pad fill
    if (t < 256) sA[t] = (t < ngrp) ? ((rh[t] + 3) & ~3) : 0;
    __syncthreads();
    for (int off = 1; off < 256; off <<= 1) {
        int v = 0;
        if (t < 256) v = sA[t] + ((t >= off) ? sA[t - off] : 0);
        __syncthreads();
        if (t < 256) sA[t] = v;
        __syncthreads();
    }
    if (t < ngrp) {
        const int pc = (rh[t] + 3) & ~3;
        const int gb = sA[t] - pc;
        grpBase[t] = gb;
        gcur[t]    = gb;
        for (int k = gb + rh[t]; k < gb + pc; ++k) { colS[k] = 0; valS[k] = 0.f; }
    }
    __syncthreads();
    if (t == 0) grpBase[ngrp] = sA[ngrp - 1];
    __syncthreads();

    // P3: LDS->LDS scatter straight into (phase,row)-sorted position
    {
        const int lim = (base + len < STGCAP) ? (base + len) : STGCAP;
        for (int k = base; k < lim; ++k) {
            const uint2 rec = stg[k];
            const int lr = (int)(rec.x >> 16) - sstart;
            const int ph = (int)((rec.x & 0xffffu) >> 13);
            const int pos = atomicAdd(&gcur[ph * width + lr], 1);
            colS[pos] = (unsigned short)(rec.x & 0xffffu);
            valS[pos] = __uint_as_float(rec.y);
        }
    }
    __syncthreads();

    // P4: phase-major gather. Wave w owns rows lr = w+8*ri (ri<4), acc in regs.
    const int w    = t >> 6;
    const int lane = t & 63;
#define GATH(cc) hbits[(((unsigned)(cc)) << 6) | (unsigned)lane]
    float2 acc[4];
#pragma unroll
    for (int ri = 0; ri < 4; ++ri) acc[ri] = make_float2(0.f, 0.f);

    for (int ph = 0; ph < NPH; ++ph) {
#pragma unroll
        for (int ri = 0; ri < 4; ++ri) {
            const int lr = w + ri * 8;
            if (lr < width) {
                const int g = ph * width + lr;
                const int s = grpBase[g];
                const int e = grpBase[g + 1];
                int i = s;
                for (; i + 8 <= e; i += 8) {
                    const uint2  ca = *(const uint2*)&colS[i];
                    const uint2  cb = *(const uint2*)&colS[i + 4];
                    const float4 v0 = *(const float4*)&valS[i];
                    const float4 v1 = *(const float4*)&valS[i + 4];
                    unsigned hb[8];
                    hb[0] = GATH(ca.x & 0xffffu);
                    hb[1] = GATH(ca.x >> 16);
                    hb[2] = GATH(ca.y & 0xffffu);
                    hb[3] = GATH(ca.y >> 16);
                    hb[4] = GATH(cb.x & 0xffffu);
                    hb[5] = GATH(cb.x >> 16);
                    hb[6] = GATH(cb.y & 0xffffu);
                    hb[7] = GATH(cb.y >> 16);
                    const float vv[8] = {v0.x, v0.y, v0.z, v0.w, v1.x, v1.y, v1.z, v1.w};
#pragma unroll
                    for (int j = 0; j < 8; ++j) {
                        acc[ri].x += vv[j] * __uint_as_float(hb[j] << 16);
                        acc[ri].y += vv[j] * __uint_as_float(hb[j] & 0xffff0000u);
                    }
                }
                if (i < e) {   // exactly one 4-wide remainder (padded to 4)
                    const uint2  ca = *(const uint2*)&colS[i];
                    const float4 v0 = *(const float4*)&valS[i];
                    unsigned hb[4];
                    hb[0] = GATH(ca.x & 0xffffu);
                    hb[1] = GATH(ca.x >> 16);
                    hb[2] = GATH(ca.y & 0xffffu);
                    hb[3] = GATH(ca.y >> 16);
                    const float vv[4] = {v0.x, v0.y, v0.z, v0.w};
#pragma unroll
                    for (int j = 0; j < 4; ++j) {
                        acc[ri].x += vv[j] * __uint_as_float(hb[j] << 16);
                        acc[ri].y += vv[j] * __uint_as_float(hb[j] & 0xffff0000u);
                    }
                }
            }
        }
    }
#undef GATH

#pragma unroll
    for (int ri = 0; ri < 4; ++ri) {
        const int lr = w + ri * 8;
        if (lr < width) {
            const int row = sstart + lr;
            ((float2*)out)[(size_t)row * 64 + lane] = acc[ri];
        }
    }
}

extern "C" void kernel_launch(void* const* d_in, const int* in_sizes, int n_in,
                              void* d_out, int out_size, void* d_ws, size_t ws_size,
                              hipStream_t stream) {
    const float* X     = (const float*)d_in[0];
    const float* W     = (const float*)d_in[1];
    const float* alpha = (const float*)d_in[2];
    const int*   rows  = (const int*)d_in[3];
    const int*   cols  = (const int*)d_in[4];
    const float* vals  = (const float*)d_in[5];
    float* out = (float*)d_out;

    // workspace layout (33,049,088 B <= proven 33,870,176 footprint)
    char* ws = (char*)d_ws;
    unsigned*       hbits = (unsigned*)(ws + 0);              // 12,800,000 B
    unsigned short* hb16  = (unsigned short*)(ws + 0);        // same bytes, u16 view
    uint2*          out1  = (uint2*)(ws + 12800000);          // 256*9375*8 = 19,200,000 B
    unsigned short* off1  = (unsigned short*)(ws + 32000000); // 256*2049*2 =  1,049,088 B

    hipLaunchKernelGGL(k_front, dim3(FGRID), dim3(512), 0, stream,
                       X, W, rows, cols, vals, alpha, hb16, out1, off1);
    hipLaunchKernelGGL(k_agg, dim3(NBUK), dim3(512), 0, stream,
                       hbits, out1, off1, out);
}